// Round 15
// baseline (393.470 us; speedup 1.0000x reference)
//
#include <hip/hip_runtime.h>
#include <hip/hip_bf16.h>
#include <cstdint>
#include <type_traits>

#define GLOBAL_AS __attribute__((address_space(1)))
#define LDS_AS    __attribute__((address_space(3)))

typedef short bf16x8 __attribute__((ext_vector_type(8)));
typedef short short8_t __attribute__((ext_vector_type(8)));
typedef float f32x4  __attribute__((ext_vector_type(4)));

static constexpr int E_DIM = 1024;
static constexpr int HD = 64;
static constexpr int QKV_STRIDE = 3072;
static constexpr int KDIM = 1024;        // K for both GEMMs
static constexpr int NTK  = KDIM / 64;   // 16 K-tiles
static constexpr int NIT  = NTK / 2;     // 8 iterations (2 K-tiles each)

__device__ __forceinline__ float b2f(short s) {
    union { unsigned u; float f; } x;
    x.u = ((unsigned)(unsigned short)s) << 16;
    return x.f;
}
__device__ __forceinline__ short f2b(float f) {
    union { float f; unsigned u; } x; x.f = f;
    unsigned r = x.u + 0x7FFF + ((x.u >> 16) & 1);
    return (short)(r >> 16);
}

// ---- fused prep: x->bf16, Wq/Wk/Wv->Wqkvb, Wo->Wob, bias concat ----
__global__ __launch_bounds__(256) void k_prep(
    const float* __restrict__ x,
    const float* __restrict__ Wq, const float* __restrict__ Wk,
    const float* __restrict__ Wv, const float* __restrict__ Wo,
    const float* __restrict__ bq, const float* __restrict__ bk,
    const float* __restrict__ bv,
    short* __restrict__ xb, short* __restrict__ Wqkvb, short* __restrict__ Wob,
    float* __restrict__ bqkv, int n4x, int n4w)
{
    int i = blockIdx.x * 256 + threadIdx.x;
    const float* src;
    short* dst;
    int j;
    if (i < n4x)                       { src = x;  dst = xb;                  j = i; }
    else if (i < n4x + n4w)            { src = Wq; dst = Wqkvb;               j = i - n4x; }
    else if (i < n4x + 2 * n4w)        { src = Wk; dst = Wqkvb + 4 * n4w;     j = i - n4x - n4w; }
    else if (i < n4x + 3 * n4w)        { src = Wv; dst = Wqkvb + 8 * n4w;     j = i - n4x - 2 * n4w; }
    else if (i < n4x + 4 * n4w)        { src = Wo; dst = Wob;                 j = i - n4x - 3 * n4w; }
    else {
        int b = i - (n4x + 4 * n4w);
        if (b < 768) {
            #pragma unroll
            for (int e = 0; e < 4; ++e) {
                int idx = b * 4 + e;
                float v = (idx < 1024) ? bq[idx] : (idx < 2048 ? bk[idx - 1024] : bv[idx - 2048]);
                bqkv[idx] = v;
            }
        }
        return;
    }
    float4 v = reinterpret_cast<const float4*>(src)[j];
    short4 o;
    o.x = f2b(v.x); o.y = f2b(v.y); o.z = f2b(v.z); o.w = f2b(v.w);
    reinterpret_cast<short4*>(dst)[j] = o;
}

// ==== 256x256 bf16 GEMM — MFMA-first, 4 phases/iter, protocol-correct ====
// INVARIANT (R3/R14 lesson): every read of a freshly staged LDS region
// follows {vm-wait retiring that region's loads} -> {s_barrier} -> {read}.
//  p1: BAR; MM2(0)(E); rd af1(E); stage E2-B(4); VM4  [retires O's 8]
//  p2: BAR; MM2(4)(E); stage E2-A(4); rd af0/bfA/bfB(O)   [O secured @p1+BAR]
//  p3: BAR; MM2(0)(O); rd af1(O); stage O2-B(4); VM4  [retires E2's 8]
//  p4: BAR; MM2(4)(O); stage O2-A(4); rd af0/bfA/bfB(E2)  [E2 secured @p3+BAR]
// FIFO/wave: enter p1 with 8 (O); +4 -> VM4 -> 4; p2 +4 -> 8 (E2); p3 +4 ->
// VM4 -> 4; p4 +4 -> 8 (O2). Overwrites: each stage target's last LDS read
// issued before the barrier preceding the stage (B: prev p4/p2 tail; A:
// p1/p3 tail) -> >=1 barrier slack. Prologue: t0+t1 (16), VM8 retires t0,
// BAR, read t0 frags. Tail: clamped dup stages into dead regions; final
// p4-tail reads dead (regs unconsumed). Reg liveness: af reused (af0/af1
// read post-MM consuming it); bfA/bfB re-read post-MM2(4).
template <typename OutT>
__global__ __launch_bounds__(512, 2) void k_gemm256(
    const short* __restrict__ A,    // [M][KDIM]
    const short* __restrict__ Bm,   // [N][KDIM]
    const float* __restrict__ bias, // [N]
    OutT* __restrict__ C,           // [M][N]
    int NT_N, int N)
{
    __shared__ short lds[65536];   // [buf]*32768 + [mat]*16384 + [half]*8192

    const int tid  = threadIdx.x;
    const int lane = tid & 63;
    const int wv   = tid >> 6;
    const int wr   = wv >> 2;       // 0..1 M half
    const int wc   = wv & 3;        // 0..3 N quarter
    const int frow = lane & 15;
    const int ks   = lane >> 4;     // k-slot within 32-k
    const int sw   = frow & 7;      // read-side swizzle key
    const int sl0  = ((0 + ks) ^ sw) * 8;   // kk=0 slot offset (shorts)
    const int sl1  = ((4 + ks) ^ sw) * 8;   // kk=1

    // bijective XCD swizzle (grid%8==0), n-fastest (neighbors share A-panel)
    const int nwg = gridDim.x, nper = nwg >> 3, bid = blockIdx.x;
    const int swz = (bid & 7) * nper + (bid >> 3);
    const int m0  = (swz / NT_N) * 256;
    const int n0  = (swz % NT_N) * 256;

    // read bases (shorts, within buf)
    const int ArdBase = wr * 8192;
    const int BrdBase = 16384 + (wc >> 1) * 8192 + (wc & 1) * 4096;

    // staging: thread covers rows srow and srow+64 of a 128-row half
    const int srow = tid >> 3;                       // 0..63
    const int ssl  = ((tid & 7) ^ (srow & 7)) * 8;   // pre-swizzled source slot
    const int sdst = tid * 8;                        // linear LDS dest

#define GLD(SRC, DST) __builtin_amdgcn_global_load_lds(                            \
        (const GLOBAL_AS short*)(SRC), (LDS_AS short*)(DST), 16, 0, 0)
#define STAGE_A(BUF, HALF, T) do {                                                 \
    const short* s_ = A + (size_t)(m0 + (HALF) * 128 + srow) * KDIM + (T) * 64 + ssl; \
    short* d_ = &lds[(BUF) * 32768 + (HALF) * 8192 + sdst];                        \
    GLD(s_, d_);  GLD(s_ + (size_t)64 * KDIM, d_ + 4096);                          \
} while (0)
#define STAGE_B(BUF, HALF, T) do {                                                 \
    const short* s_ = Bm + (size_t)(n0 + (HALF) * 128 + srow) * KDIM + (T) * 64 + ssl; \
    short* d_ = &lds[(BUF) * 32768 + 16384 + (HALF) * 8192 + sdst];                \
    GLD(s_, d_);  GLD(s_ + (size_t)64 * KDIM, d_ + 4096);                          \
} while (0)

#define RD_A(BUF, MIB) do {                                                        \
    _Pragma("unroll")                                                              \
    for (int m_ = 0; m_ < 4; ++m_) {                                               \
        const short* p_ = &lds[(BUF) * 32768 + ArdBase + ((MIB) + m_) * 1024 + frow * 64]; \
        af[m_][0] = *(const bf16x8*)(p_ + sl0);                                    \
        af[m_][1] = *(const bf16x8*)(p_ + sl1);                                    \
    }                                                                              \
} while (0)
#define RD_B(BUF, NIB, BF) do {                                                    \
    _Pragma("unroll")                                                              \
    for (int n_ = 0; n_ < 2; ++n_) {                                               \
        const short* p_ = &lds[(BUF) * 32768 + BrdBase + ((NIB) + n_) * 1024 + frow * 64]; \
        BF[n_][0] = *(const bf16x8*)(p_ + sl0);                                    \
        BF[n_][1] = *(const bf16x8*)(p_ + sl1);                                    \
    }                                                                              \
} while (0)

// 32-MFMA burst: acc[MB..MB+3][0..3], both k-halves.
#define MM2(MB) do {                                                               \
    __builtin_amdgcn_s_setprio(1);                                                 \
    _Pragma("unroll")                                                              \
    for (int m_ = 0; m_ < 4; ++m_) {                                               \
        _Pragma("unroll")                                                          \
        for (int n_ = 0; n_ < 2; ++n_) {                                           \
            acc[(MB)+m_][n_] = __builtin_amdgcn_mfma_f32_16x16x32_bf16(            \
                af[m_][0], bfA[n_][0], acc[(MB)+m_][n_], 0, 0, 0);                 \
            acc[(MB)+m_][n_] = __builtin_amdgcn_mfma_f32_16x16x32_bf16(            \
                af[m_][1], bfA[n_][1], acc[(MB)+m_][n_], 0, 0, 0);                 \
            acc[(MB)+m_][2+n_] = __builtin_amdgcn_mfma_f32_16x16x32_bf16(          \
                af[m_][0], bfB[n_][0], acc[(MB)+m_][2+n_], 0, 0, 0);               \
            acc[(MB)+m_][2+n_] = __builtin_amdgcn_mfma_f32_16x16x32_bf16(          \
                af[m_][1], bfB[n_][1], acc[(MB)+m_][2+n_], 0, 0, 0);               \
        }                                                                          \
    }                                                                              \
    __builtin_amdgcn_s_setprio(0);                                                 \
} while (0)

#define BAR   __builtin_amdgcn_s_barrier()
#define VM4   asm volatile("s_waitcnt vmcnt(4)" ::: "memory")
#define VM8   asm volatile("s_waitcnt vmcnt(8)" ::: "memory")

    f32x4 acc[8][4];
    #pragma unroll
    for (int i = 0; i < 8; ++i)
        #pragma unroll
        for (int j = 0; j < 4; ++j)
            acc[i][j] = (f32x4){0.f, 0.f, 0.f, 0.f};

    bf16x8 af[4][2], bfA[2][2], bfB[2][2];

    // prologue: t0 (8) + t1 (8); VM8 retires t0; BAR; read t0 frags.
    STAGE_A(0, 0, 0);  STAGE_A(0, 1, 0);  STAGE_B(0, 0, 0);  STAGE_B(0, 1, 0);
    STAGE_A(1, 0, 1);  STAGE_A(1, 1, 1);  STAGE_B(1, 0, 1);  STAGE_B(1, 1, 1);
    VM8;  BAR;
    RD_A(0, 0);  RD_B(0, 0, bfA);  RD_B(0, 2, bfB);

    #pragma unroll 1
    for (int it = 0; it < NIT; ++it) {
        const int tb = (2 * it + 2 <= 15) ? 2 * it + 2 : 15;  // E2 -> buf0
        const int tc = (2 * it + 3 <= 15) ? 2 * it + 3 : 15;  // O2 -> buf1

        // p1: E upper
        BAR;
        MM2(0);
        RD_A(0, 4);                               // af1(E)
        STAGE_B(0, 0, tb);  STAGE_B(0, 1, tb);    // E2-B -> buf0-B
        VM4;                                      // retires O's 8 loads
        // p2: E lower  (O reads legal: secured @p1 VM4 + BAR)
        BAR;
        MM2(4);
        STAGE_A(0, 0, tb);  STAGE_A(0, 1, tb);    // E2-A -> buf0-A
        RD_A(1, 0);  RD_B(1, 0, bfA);  RD_B(1, 2, bfB);
        // p3: O upper
        BAR;
        MM2(0);
        RD_A(1, 4);                               // af1(O)
        STAGE_B(1, 0, tc);  STAGE_B(1, 1, tc);    // O2-B -> buf1-B
        VM4;                                      // retires E2's 8 loads
        // p4: O lower  (E2 reads legal: secured @p3 VM4 + BAR)
        BAR;
        MM2(4);
        STAGE_A(1, 0, tc);  STAGE_A(1, 1, tc);    // O2-A -> buf1-A
        RD_A(0, 0);  RD_B(0, 0, bfA);  RD_B(0, 2, bfB);
    }

    asm volatile("s_waitcnt vmcnt(0)" ::: "memory");   // drain tail dups

    // epilogue: C/D layout col = lane&15, row = (lane>>4)*4 + r
    const int crow = (lane >> 4) * 4;
    const int ccol = lane & 15;
    float bv4[4];
    #pragma unroll
    for (int ni = 0; ni < 4; ++ni)
        bv4[ni] = bias[n0 + wc * 64 + ni * 16 + ccol];
    #pragma unroll
    for (int mi = 0; mi < 8; ++mi) {
        #pragma unroll
        for (int r = 0; r < 4; ++r) {
            const size_t rowg = (size_t)(m0 + wr * 128 + mi * 16 + crow + r) * N;
            #pragma unroll
            for (int ni = 0; ni < 4; ++ni) {
                const int col = n0 + wc * 64 + ni * 16 + ccol;
                float v = acc[mi][ni][r] + bv4[ni];
                if constexpr (std::is_same<OutT, float>::value) {
                    C[rowg + col] = v;
                } else {
                    C[rowg + col] = f2b(v);
                }
            }
        }
    }
#undef GLD
#undef STAGE_A
#undef STAGE_B
#undef RD_A
#undef RD_B
#undef MM2
#undef BAR
#undef VM4
#undef VM8
}

// ---------------- per-token head-mixing attention ----------------------
__global__ __launch_bounds__(256) void k_attn(
    const short* __restrict__ QKV, short* __restrict__ O)
{
    __shared__ short Ks[16][1032];
    __shared__ short Vs[16][1032];

    const int tid = threadIdx.x;
    const int tok0 = blockIdx.x * 16;

    for (int i = tid; i < 2048; i += 256) {
        int t = i >> 7;
        int j = i & 127;
        const size_t base = (size_t)(tok0 + t) * QKV_STRIDE;
        *reinterpret_cast<short8_t*>(&Ks[t][j * 8]) =
            *reinterpret_cast<const short8_t*>(&QKV[base + 1024 + j * 8]);
        *reinterpret_cast<short8_t*>(&Vs[t][j * 8]) =
            *reinterpret_cast<const short8_t*>(&QKV[base + 2048 + j * 8]);
    }
    __syncthreads();

    const int tl = tid >> 4;
    const int h  = tid & 15;

    float qf[64];
    const short* qp = QKV + (size_t)(tok0 + tl) * QKV_STRIDE + h * HD;
    #pragma unroll
    for (int i = 0; i < 8; ++i) {
        short8_t v = *reinterpret_cast<const short8_t*>(&qp[i * 8]);
        #pragma unroll
        for (int j = 0; j < 8; ++j) qf[i * 8 + j] = b2f(v[j]);
    }

    float s[16];
    #pragma unroll
    for (int g = 0; g < 16; ++g) {
        float a = 0.f;
        #pragma unroll
        for (int i = 0; i < 8; ++i) {
            short8_t kv = *reinterpret_cast<const short8_t*>(&Ks[tl][g * HD + i * 8]);
            #pragma unroll
            for (int j = 0; j < 8; ++j) a += qf[i * 8 + j] * b2f(kv[j]);
        }
        s[g] = a * 0.125f;
    }
    float mx = s[0];
    #pragma unroll
    for (int g = 1; g < 16; ++g) mx = fmaxf(mx, s[g]);
    float l = 0.f;
    #pragma unroll
    for (int g = 0; g < 16; ++g) { s[g] = __expf(s[g] - mx); l += s[g]; }
    const float inv = 1.f / l;
    #pragma unroll
    for (int g = 0; g < 16; ++g) s[g] *= inv;

    short* op = O + (size_t)(tok0 + tl) * E_DIM + h * HD;
    #pragma unroll
    for (int c = 0; c < 4; ++c) {
        float a[16];
        #pragma unroll
        for (int j = 0; j < 16; ++j) a[j] = 0.f;
        #pragma unroll
        for (int g = 0; g < 16; ++g) {
            short8_t v0 = *reinterpret_cast<const short8_t*>(&Vs[tl][g * HD + c * 16]);
            short8_t v1 = *reinterpret_cast<const short8_t*>(&Vs[tl][g * HD + c * 16 + 8]);
            #pragma unroll
            for (int j = 0; j < 8; ++j) {
                a[j]     += s[g] * b2f(v0[j]);
                a[8 + j] += s[g] * b2f(v1[j]);
            }
        }
        short8_t o0, o1;
        #pragma unroll
        for (int j = 0; j < 8; ++j) { o0[j] = f2b(a[j]); o1[j] = f2b(a[8 + j]); }
        *reinterpret_cast<short8_t*>(&op[c * 16])     = o0;
        *reinterpret_cast<short8_t*>(&op[c * 16 + 8]) = o1;
    }
}

extern "C" void kernel_launch(void* const* d_in, const int* in_sizes, int n_in,
                              void* d_out, int out_size, void* d_ws, size_t ws_size,
                              hipStream_t stream) {
    const float* x  = (const float*)d_in[0];
    const float* Wq = (const float*)d_in[1];
    const float* bq = (const float*)d_in[2];
    const float* Wk = (const float*)d_in[3];
    const float* bk = (const float*)d_in[4];
    const float* Wv = (const float*)d_in[5];
    const float* bv = (const float*)d_in[6];
    const float* Wo = (const float*)d_in[7];
    const float* bo = (const float*)d_in[8];
    float* out = (float*)d_out;

    const int T = in_sizes[0] / E_DIM;      // 32768 tokens
    char* ws = (char*)d_ws;
    const size_t SZ_X    = (size_t)T * E_DIM * 2;
    const size_t SZ_WQKV = (size_t)3 * E_DIM * E_DIM * 2;
    const size_t SZ_W    = (size_t)E_DIM * E_DIM * 2;
    const size_t SZ_B    = 3072 * sizeof(float) + 4096;

    short* xb    = (short*)(ws);
    short* Wqkvb = (short*)(ws + SZ_X);
    short* Wob   = (short*)(ws + SZ_X + SZ_WQKV);
    float* bqkv  = (float*)(ws + SZ_X + SZ_WQKV + SZ_W);
    short* QKVb  = (short*)(ws + SZ_X + SZ_WQKV + SZ_W + SZ_B);
    short* Ab    = xb;   // reuse x-bf16 buffer for attention output

    const int n4x = T * E_DIM / 4;          // 8M float4
    const int n4w = E_DIM * E_DIM / 4;      // 256K float4
    const int nprep = n4x + 4 * n4w + 768;
    k_prep<<<dim3((nprep + 255) / 256), dim3(256), 0, stream>>>(
        x, Wq, Wk, Wv, Wo, bq, bk, bv, xb, Wqkvb, Wob, bqkv, n4x, n4w);

    // fused QKV GEMM: [T][3072]
    k_gemm256<short><<<dim3((T / 256) * (QKV_STRIDE / 256)), dim3(512), 0, stream>>>(
        xb, Wqkvb, bqkv, QKVb, QKV_STRIDE / 256, QKV_STRIDE);

    k_attn<<<dim3(T / 16), dim3(256), 0, stream>>>(QKVb, Ab);

    // output GEMM: [T][1024] fp32
    k_gemm256<float><<<dim3((T / 256) * (E_DIM / 256)), dim3(512), 0, stream>>>(
        Ab, Wob, bo, out, E_DIM / 256, E_DIM);
}